// Round 12
// baseline (161.611 us; speedup 1.0000x reference)
//
#include <hip/hip_runtime.h>

#define EG   16000   // graph edges
#define NG   1000    // graph_size (block rows/cols)
#define BB   32      // batch
#define SIZE 16000   // feature length (NG*16)
#define CAPW 32      // per-wave capacity (Poisson(4): P(>32) ~ 1e-20)

typedef float f32x4 __attribute__((ext_vector_type(4)));

// ---- kernel 1: gather strided edge headers into dense pk[e]=(t0<<10)|t1 ----
// Writes every entry each launch: ws poison is never read. No memset needed.
__global__ __launch_bounds__(256) void pack_kernel(
    const int* __restrict__ rows, const int* __restrict__ cols,
    int* __restrict__ pk)
{
    int e = blockIdx.x * 256 + threadIdx.x;
    if (e < EG) {
        int t0 = rows[(long)e << 8] >> 4;   // rows[e*256] = t0*16
        int t1 = cols[(long)e << 8] >> 4;   // cols[e*256] = t1*16
        pk[e] = (t0 << 10) | t1;            // 20 bits
    }
}

// ---- kernel 2: BARRIER-FREE WAVES. One block per bin; each of the 4 waves ----
// scans its own pk quarter, compacts its own edges, and free-runs its private
// depth-1 pipelined edge loop in its own LDS slots. No __syncthreads in the
// main loop (waves share nothing there; same-wave ds ordering = compiler
// lgkmcnt). Only 2 barriers: before/inside the cross-wave reduce epilogue.
// Rationale (r10/r11): TLP increase didn't move the ~35us spmm -> stall was
// the per-iteration lockstep (vmcnt0 + barrier x all 4 waves); decouple waves.
// NOTE (r8/r9): no in-kernel grid barriers (coop launch breaks graph capture;
// spin barriers ~+130us). NOTE (r3): stores line-clustered, wave-private.
__global__ __launch_bounds__(256, 4) void spmm_kernel(
    const float* __restrict__ wm, const float* __restrict__ wlv,
    const float* __restrict__ ew, const float* __restrict__ x,
    const float* __restrict__ bm, const float* __restrict__ blv,
    const float* __restrict__ eb, const int* __restrict__ pk,
    float* __restrict__ out)
{
    __shared__ f32x4 vt[4][2][64];    // [wave][buf][i*4+jg] sampled weights (8KB)
    __shared__ f32x4 xs[4][2][160];   // [wave][buf][b*5+q]  x rows, pad-5 (20KB)
    __shared__ int   sl[4][CAPW];     // per-wave packed (e<<10)|t1
    __shared__ int   scnt[4];

    int g    = blockIdx.x;
    int tid  = threadIdx.x;
    int wave = tid >> 6;
    int lane = tid & 63;

    if (lane == 0) scnt[wave] = 0;    // own wave's counter; no barrier needed

    // ---- phase 1 (per-wave): scan own pk quarter, compact own edges ----
    const int4* pk4 = (const int4*)pk;
    int base = wave * 1000;           // 1000 int4 = 4000 edges per wave
    for (int c = base + lane; c < base + 1000; c += 64) {
        int4 v = pk4[c];
        int e0 = c << 2;
        if ((v.x >> 10) == g) { int p = atomicAdd(&scnt[wave], 1); if (p < CAPW) sl[wave][p] = ((e0    ) << 10) | (v.x & 1023); }
        if ((v.y >> 10) == g) { int p = atomicAdd(&scnt[wave], 1); if (p < CAPW) sl[wave][p] = ((e0 + 1) << 10) | (v.y & 1023); }
        if ((v.z >> 10) == g) { int p = atomicAdd(&scnt[wave], 1); if (p < CAPW) sl[wave][p] = ((e0 + 2) << 10) | (v.z & 1023); }
        if ((v.w >> 10) == g) { int p = atomicAdd(&scnt[wave], 1); if (p < CAPW) sl[wave][p] = ((e0 + 3) << 10) | (v.w & 1023); }
    }
    int nw = scnt[wave];              // own-wave atomics: lgkmcnt, no barrier
    nw = nw < CAPW ? nw : CAPW;

    // ---- phase 2 (per-wave, barrier-free): pipelined edge loop ----
    int jg  = lane & 3;               // col group (4 cols)
    int cb2 = lane >> 2;              // batch 0..15 (acc0: cb2, acc1: cb2+16)

    f32x4 acc0 = {0.f,0.f,0.f,0.f}, acc1 = {0.f,0.f,0.f,0.f};
    f32x4 m4, l4, g4, xv0, xv1;       // staged regs (in flight across compute)

    auto issue = [&](int idx) {             // global loads only (no LDS writes)
        int pkv = sl[wave][idx];            // LDS broadcast (own wave's list)
        int e   = pkv >> 10;
        int t1  = pkv & 1023;
        long wq = ((long)e << 6) + lane;
        m4 = ((const f32x4*)wm)[wq];        // 3 x b128, coalesced 1KB/wave
        l4 = ((const f32x4*)wlv)[wq];
        g4 = ((const f32x4*)ew)[wq];
        const f32x4* x4 = (const f32x4*)x;
        int c0 = lane, c1 = lane + 64;      // chunk = (b = c>>2, q = c&3)
        xv0 = x4[(long)(c0 >> 2) * (SIZE/4) + (t1 << 2) + (c0 & 3)];
        xv1 = x4[(long)(c1 >> 2) * (SIZE/4) + (t1 << 2) + (c1 & 3)];
    };
    auto writeb = [&](int buf) {            // vmcnt wait lands here (T14)
        f32x4 v;
        v.x = g4.x * __expf(l4.x) + m4.x;
        v.y = g4.y * __expf(l4.y) + m4.y;
        v.z = g4.z * __expf(l4.z) + m4.z;
        v.w = g4.w * __expf(l4.w) + m4.w;
        vt[wave][buf][lane] = v;            // chunk lane = (i=lane>>2, jg=lane&3)
        int c0 = lane, c1 = lane + 64;
        xs[wave][buf][(c0 >> 2) * 5 + (c0 & 3)] = xv0;
        xs[wave][buf][(c1 >> 2) * 5 + (c1 & 3)] = xv1;
    };
    auto compute = [&](int buf) {           // own-wave LDS: lgkmcnt only
        f32x4 a0 = xs[wave][buf][ cb2       * 5 + 0];
        f32x4 a1 = xs[wave][buf][ cb2       * 5 + 1];
        f32x4 a2 = xs[wave][buf][ cb2       * 5 + 2];
        f32x4 a3 = xs[wave][buf][ cb2       * 5 + 3];
        f32x4 b0 = xs[wave][buf][(cb2 + 16) * 5 + 0];
        f32x4 b1 = xs[wave][buf][(cb2 + 16) * 5 + 1];
        f32x4 b2 = xs[wave][buf][(cb2 + 16) * 5 + 2];
        f32x4 b3 = xs[wave][buf][(cb2 + 16) * 5 + 3];
        float xra[16] = {a0.x,a0.y,a0.z,a0.w, a1.x,a1.y,a1.z,a1.w,
                         a2.x,a2.y,a2.z,a2.w, a3.x,a3.y,a3.z,a3.w};
        float xrb[16] = {b0.x,b0.y,b0.z,b0.w, b1.x,b1.y,b1.z,b1.w,
                         b2.x,b2.y,b2.z,b2.w, b3.x,b3.y,b3.z,b3.w};
        #pragma unroll
        for (int i = 0; i < 16; ++i) {
            f32x4 w = vt[wave][buf][(i << 2) + jg];  // 16-lane broadcast chunks
            acc0 += w * xra[i];             // 4 FMA (static index after unroll)
            acc1 += w * xrb[i];
        }
    };

    if (nw > 0) { issue(0); writeb(0); }    // prologue
    for (int it = 0; it < nw; ++it) {       // wave free-runs its own edges
        if (it + 1 < nw) issue(it + 1);     // next edge's globals in flight
        compute(it & 1);
        if (it + 1 < nw) writeb((it + 1) & 1);
    }

    // ---- epilogue: the only two barriers in the kernel ----
    __syncthreads();                        // all waves done with xs (overlay)
    f32x4* sred = &xs[0][0][0];             // 512 f32x4 overlay
    sred[(wave << 7) + (lane << 1) + 0] = acc0;
    sred[(wave << 7) + (lane << 1) + 1] = acc1;
    __syncthreads();
    if (tid < 128) {
        int cb  = tid >> 2;                // batch 0..31
        int jgf = tid & 3;
        int h   = cb >> 4;                 // which accumulator half
        int sl_ = ((cb & 15) << 2) + jgf;  // lane in wave
        f32x4 s = sred[(0 << 7) + (sl_ << 1) + h]
                + sred[(1 << 7) + (sl_ << 1) + h]
                + sred[(2 << 7) + (sl_ << 1) + h]
                + sred[(3 << 7) + (sl_ << 1) + h];
        int r0 = (g << 4) + (jgf << 2);    // 16B-aligned
        f32x4 b4 = *(const f32x4*)&bm[r0];
        f32x4 v4 = *(const f32x4*)&blv[r0];
        f32x4 e4 = *(const f32x4*)&eb[r0];
        f32x4 o;
        o.x = s.x + (e4.x * __expf(v4.x) + b4.x);
        o.y = s.y + (e4.y * __expf(v4.y) + b4.y);
        o.z = s.z + (e4.z * __expf(v4.z) + b4.z);
        o.w = s.w + (e4.w * __expf(v4.w) + b4.w);
        *(f32x4*)&out[(long)cb * SIZE + r0] = o;
    }
    if (g == 0 && tid == 0) out[(long)BB * SIZE] = 0.0f;   // kl scalar
}

extern "C" void kernel_launch(void* const* d_in, const int* in_sizes, int n_in,
                              void* d_out, int out_size, void* d_ws, size_t ws_size,
                              hipStream_t stream) {
    const float* x   = (const float*)d_in[0];
    const float* wm  = (const float*)d_in[1];
    const float* wlv = (const float*)d_in[2];
    const float* bm  = (const float*)d_in[3];
    const float* blv = (const float*)d_in[4];
    const float* ew  = (const float*)d_in[5];
    const float* eb  = (const float*)d_in[6];
    const int* rows  = (const int*)d_in[7];
    const int* cols  = (const int*)d_in[8];
    float* out = (float*)d_out;

    int* pk = (int*)d_ws;                 // 16000 ints = 64KB dense edge headers

    pack_kernel<<<(EG + 255) / 256, 256, 0, stream>>>(rows, cols, pk);
    spmm_kernel<<<NG, 256, 0, stream>>>(wm, wlv, ew, x, bm, blv, eb, pk, out);
}

// Round 14
// 137.769 us; speedup vs baseline: 1.1731x; 1.1731x over previous
//
#include <hip/hip_runtime.h>

#define EG   16000   // graph edges
#define NG   1000    // graph_size (block rows/cols)
#define BB   32      // batch
#define SIZE 16000   // feature length (NG*16)
#define CAP  64      // per-bin capacity (Poisson(16): P(>64) ~ 1e-18)

typedef float f32x4 __attribute__((ext_vector_type(4)));

// ---- kernel 1: sequential-stream v-precompute + header pack ----
// w arrays are touched ONCE; streaming them sequentially here runs at HBM
// ceiling (r12 showed bin-order 1KB-tile reads crawl at 1.6 TB/s). spmm then
// re-reads only the 16MB v array (L2/L3-warm). Headers packed in same pass.
// Grid 4000x256 covers NNZ/4 = 1,024,000 f32x4 chunks exactly. No memset:
// every v/pk entry is written each launch (ws poison never read).
__global__ __launch_bounds__(256) void gather_kernel(
    const float* __restrict__ wm, const float* __restrict__ wlv,
    const float* __restrict__ ew, const int* __restrict__ rows,
    const int* __restrict__ cols, float* __restrict__ v, int* __restrict__ pk)
{
    int t = blockIdx.x * 256 + threadIdx.x;    // f32x4 chunk index
    const f32x4* wm4  = (const f32x4*)wm;
    const f32x4* wlv4 = (const f32x4*)wlv;
    const f32x4* ew4  = (const f32x4*)ew;
    f32x4 m4 = __builtin_nontemporal_load(&wm4[t]);   // single-use streams
    f32x4 l4 = __builtin_nontemporal_load(&wlv4[t]);
    f32x4 g4 = __builtin_nontemporal_load(&ew4[t]);
    f32x4 o;
    o.x = g4.x * __expf(l4.x) + m4.x;
    o.y = g4.y * __expf(l4.y) + m4.y;
    o.z = g4.z * __expf(l4.z) + m4.z;
    o.w = g4.w * __expf(l4.w) + m4.w;
    ((f32x4*)v)[t] = o;                         // normal store: keep L2-resident
    if (t < EG)
        pk[t] = ((rows[(long)t << 8] >> 4) << 10) | (cols[(long)t << 8] >> 4);
}

// ---- kernel 2: r10 lockstep spmm, consuming precomputed v ----
// One block per bin; scan dense pk (L2), compact own edges to LDS; lockstep
// 4 edges/iteration (1 per wave), depth-1 T14 staging; per edge per wave:
// 1 v-b128 + 2 x-b128 (was 3w+2x; exp gone). Compute is quad-structured
// (no 16-float register arrays -- r12's 37MB scratch-spill lesson).
// NOTE (r8/r9): no in-kernel grid barriers (coop launch breaks graph capture;
// spin barriers ~+130us). NOTE (r3): stores line-clustered, wave-private.
// NOTE (r12): don't free-run waves (max-Poisson imbalance + reg pressure).
__global__ __launch_bounds__(256, 4) void spmm_kernel(
    const float* __restrict__ v, const float* __restrict__ x,
    const float* __restrict__ bm, const float* __restrict__ blv,
    const float* __restrict__ eb, const int* __restrict__ pk,
    float* __restrict__ out)
{
    __shared__ f32x4 vt[2][4][64];    // [buf][slot][i*4+jg] sampled weights (8KB)
    __shared__ f32x4 xs[2][4][160];   // [buf][slot][b*5+q]  x rows, pad-5 (20KB)
    __shared__ int   sl[CAP];         // packed (e<<10)|t1 for this bin
    __shared__ int   scnt;

    int g   = blockIdx.x;
    int tid = threadIdx.x;

    // ---- phase 1: scan dense pk, compact own edges ----
    if (tid == 0) scnt = 0;
    __syncthreads();
    const int4* pk4 = (const int4*)pk;
    for (int c = tid; c < EG / 4; c += 256) {      // 16 coalesced L2 iterations
        int4 w = pk4[c];
        int e0 = c << 2;
        if ((w.x >> 10) == g) { int p = atomicAdd(&scnt, 1); if (p < CAP) sl[p] = ((e0    ) << 10) | (w.x & 1023); }
        if ((w.y >> 10) == g) { int p = atomicAdd(&scnt, 1); if (p < CAP) sl[p] = ((e0 + 1) << 10) | (w.y & 1023); }
        if ((w.z >> 10) == g) { int p = atomicAdd(&scnt, 1); if (p < CAP) sl[p] = ((e0 + 2) << 10) | (w.z & 1023); }
        if ((w.w >> 10) == g) { int p = atomicAdd(&scnt, 1); if (p < CAP) sl[p] = ((e0 + 3) << 10) | (w.w & 1023); }
    }
    __syncthreads();
    int n = scnt; n = n < CAP ? n : CAP;

    // ---- phase 2: lockstep spmm ----
    int wave = tid >> 6;              // edge slot 0..3
    int lane = tid & 63;
    int jg   = lane & 3;              // col group (4 cols)
    int cb2  = lane >> 2;             // batch 0..15 (acc0: cb2, acc1: cb2+16)

    f32x4 acc0 = {0.f,0.f,0.f,0.f}, acc1 = {0.f,0.f,0.f,0.f};
    f32x4 v4s, xv0, xv1;              // staged regs (in flight across compute)
    int iters = (n + 3) >> 2;
    bool vcur = false, vnxt = false;

    auto issue = [&](int idx) -> bool {     // global loads only (no LDS writes)
        bool val = idx < n;
        if (val) {                          // wave-uniform branch
            int pkv = sl[idx];
            int e   = pkv >> 10;
            int t1  = pkv & 1023;
            v4s = ((const f32x4*)v)[((long)e << 6) + lane];   // 1KB/wave, L2/L3-warm
            const f32x4* x4 = (const f32x4*)x;
            int c0 = lane, c1 = lane + 64;  // chunk = (b = c>>2, q = c&3)
            xv0 = x4[(long)(c0 >> 2) * (SIZE/4) + (t1 << 2) + (c0 & 3)];
            xv1 = x4[(long)(c1 >> 2) * (SIZE/4) + (t1 << 2) + (c1 & 3)];
        }
        return val;
    };
    auto writeb = [&](int buf, bool val) {  // vmcnt wait lands here (T14)
        if (val) {
            vt[buf][wave][lane] = v4s;      // chunk lane = (i=lane>>2, jg=lane&3)
            int c0 = lane, c1 = lane + 64;
            xs[buf][wave][(c0 >> 2) * 5 + (c0 & 3)] = xv0;
            xs[buf][wave][(c1 >> 2) * 5 + (c1 & 3)] = xv1;
        }
    };
    auto compute = [&](int buf, bool val) {
        if (!val) return;                   // wave-uniform
        #pragma unroll
        for (int q = 0; q < 4; ++q) {       // quad-structured: 8 f32x4 live max
            f32x4 xa = xs[buf][wave][ cb2       * 5 + q];
            f32x4 xb = xs[buf][wave][(cb2 + 16) * 5 + q];
            f32x4 w0 = vt[buf][wave][(q << 4) + 0  + jg];
            f32x4 w1 = vt[buf][wave][(q << 4) + 4  + jg];
            f32x4 w2 = vt[buf][wave][(q << 4) + 8  + jg];
            f32x4 w3 = vt[buf][wave][(q << 4) + 12 + jg];
            acc0 += w0 * xa.x; acc0 += w1 * xa.y;
            acc0 += w2 * xa.z; acc0 += w3 * xa.w;
            acc1 += w0 * xb.x; acc1 += w1 * xb.y;
            acc1 += w2 * xb.z; acc1 += w3 * xb.w;
        }
    };

    // prologue
    vcur = issue(wave);
    writeb(0, vcur);
    __syncthreads();
    // main loop: one barrier per 4-edge iteration
    for (int it = 0; it < iters; ++it) {
        bool more = (it + 1 < iters);
        if (more) vnxt = issue(((it + 1) << 2) + wave);  // globals in flight
        compute(it & 1, vcur);                            // LDS+VALU overlap
        if (more) writeb((it + 1) & 1, vnxt);
        __syncthreads();
        vcur = vnxt;
    }

    // ---- epilogue: cross-slot reduce + fused bias + exclusive store ----
    f32x4* sred = &xs[0][0][0];            // overlay: xs dead after last barrier
    sred[(wave << 7) + (lane << 1) + 0] = acc0;
    sred[(wave << 7) + (lane << 1) + 1] = acc1;
    __syncthreads();
    if (tid < 128) {
        int cb  = tid >> 2;                // batch 0..31
        int jgf = tid & 3;
        int h   = cb >> 4;                 // which accumulator half
        int sl_ = ((cb & 15) << 2) + jgf;  // lane in wave
        f32x4 s = sred[(0 << 7) + (sl_ << 1) + h]
                + sred[(1 << 7) + (sl_ << 1) + h]
                + sred[(2 << 7) + (sl_ << 1) + h]
                + sred[(3 << 7) + (sl_ << 1) + h];
        int r0 = (g << 4) + (jgf << 2);    // 16B-aligned
        f32x4 b4 = *(const f32x4*)&bm[r0];
        f32x4 v4 = *(const f32x4*)&blv[r0];
        f32x4 e4 = *(const f32x4*)&eb[r0];
        f32x4 o;
        o.x = s.x + (e4.x * __expf(v4.x) + b4.x);
        o.y = s.y + (e4.y * __expf(v4.y) + b4.y);
        o.z = s.z + (e4.z * __expf(v4.z) + b4.z);
        o.w = s.w + (e4.w * __expf(v4.w) + b4.w);
        *(f32x4*)&out[(long)cb * SIZE + r0] = o;
    }
    if (g == 0 && tid == 0) out[(long)BB * SIZE] = 0.0f;   // kl scalar
}

extern "C" void kernel_launch(void* const* d_in, const int* in_sizes, int n_in,
                              void* d_out, int out_size, void* d_ws, size_t ws_size,
                              hipStream_t stream) {
    const float* x   = (const float*)d_in[0];
    const float* wm  = (const float*)d_in[1];
    const float* wlv = (const float*)d_in[2];
    const float* bm  = (const float*)d_in[3];
    const float* blv = (const float*)d_in[4];
    const float* ew  = (const float*)d_in[5];
    const float* eb  = (const float*)d_in[6];
    const int* rows  = (const int*)d_in[7];
    const int* cols  = (const int*)d_in[8];
    float* out = (float*)d_out;

    char* ws = (char*)d_ws;
    float* v  = (float*)ws;               // 4,096,000 floats = 16MB sampled weights
    int*   pk = (int*)(ws + (size_t)EG * 256 * 4);   // 16000 ints, after v

    gather_kernel<<<(EG * 64) / 256, 256, 0, stream>>>(wm, wlv, ew, rows, cols, v, pk);
    spmm_kernel<<<NG, 256, 0, stream>>>(v, x, bm, blv, eb, pk, out);
}